// Round 1
// baseline (494.887 us; speedup 1.0000x reference)
//
#include <hip/hip_runtime.h>

#define AS1 __attribute__((address_space(1)))
#define AS3 __attribute__((address_space(3)))

typedef __attribute__((ext_vector_type(8))) short bf16x8;
typedef __attribute__((ext_vector_type(4))) float f32x4;

#define N_TOK 8192
#define CD 1024
#define ID 1024
#define BM 128
#define BN 128
#define BK 64
#define MAXMT 72

// ---- workspace layout (bytes) ----
#define XB_OFF   0LL            // x bf16 [N,C]                16MB
#define W1B_OFF  16777216LL     // W1^T bf16 [E][I][C]         16MB
#define WGB_OFF  33554432LL     // Wg^T bf16 [E][I][C]         16MB
#define W2B_OFF  50331648LL     // W2^T bf16 [E][C][I]         16MB
#define ACT_OFF  67108864LL     // act bf16 [2N][I]            32MB
#define ST_OFF   100663296LL    // slot_token int [2N]
#define SW_OFF   100728832LL    // slot_w float [2N]
#define TE_OFF   100794368LL    // tok_e int [N*2]
#define TW_OFF   100859904LL    // tok_w float [N*2]
#define META_OFF 100925440LL    // counts[16] offs[16] rank[16] TO[2][9]

static __device__ __forceinline__ unsigned short f2bf(float f) {
  union { float f; unsigned u; } v; v.f = f;
  unsigned r = v.u + 0x7fffu + ((v.u >> 16) & 1u);
  return (unsigned short)(r >> 16);
}

// ---------------- router: fp32 logits, softmax, top-2 ----------------
__global__ __launch_bounds__(256) void moe_router(
    const float* __restrict__ x, const float* __restrict__ Wr,
    const float* __restrict__ br, int* __restrict__ tok_e,
    float* __restrict__ tok_w, int* __restrict__ meta) {
  const int lane = threadIdx.x & 63;
  const int t = blockIdx.x * 4 + (threadIdx.x >> 6);
  if (t >= N_TOK) return;
  float acc[8];
#pragma unroll
  for (int e = 0; e < 8; e++) acc[e] = 0.f;
  const float* xr = x + (long)t * CD;
  for (int c = lane; c < CD; c += 64) {
    const float xv = xr[c];
    const float4 w0 = *(const float4*)(Wr + c * 8);
    const float4 w1 = *(const float4*)(Wr + c * 8 + 4);
    acc[0] += xv * w0.x; acc[1] += xv * w0.y; acc[2] += xv * w0.z; acc[3] += xv * w0.w;
    acc[4] += xv * w1.x; acc[5] += xv * w1.y; acc[6] += xv * w1.z; acc[7] += xv * w1.w;
  }
#pragma unroll
  for (int e = 0; e < 8; e++)
    for (int off = 32; off; off >>= 1) acc[e] += __shfl_xor(acc[e], off);
  if (lane == 0) {
    float lg[8];
#pragma unroll
    for (int e = 0; e < 8; e++) lg[e] = acc[e] + br[e];
    int i1 = 0; float m1v = lg[0];
#pragma unroll
    for (int e = 1; e < 8; e++) if (lg[e] > m1v) { m1v = lg[e]; i1 = e; }
    int i2 = -1; float m2v = -1e30f;
#pragma unroll
    for (int e = 0; e < 8; e++) if (e != i1 && lg[e] > m2v) { m2v = lg[e]; i2 = e; }
    float s = 0.f;
#pragma unroll
    for (int e = 0; e < 8; e++) s += __expf(lg[e] - m1v);
    const float w1v = 1.f / s;                // exp(m1-m1)/s
    const float w2v = __expf(m2v - m1v) / s;
    tok_e[2 * t] = i1; tok_e[2 * t + 1] = i2;
    tok_w[2 * t] = w1v; tok_w[2 * t + 1] = w2v;
    atomicAdd(&meta[i1], 1);        // counts plane k=0
    atomicAdd(&meta[8 + i2], 1);    // counts plane k=1
  }
}

// ---------------- offsets + tile offsets (1 thread) ----------------
__global__ void moe_offsets(int* __restrict__ meta) {
  if (threadIdx.x != 0 || blockIdx.x != 0) return;
  int* counts = meta; int* offs = meta + 16; int* TO = meta + 48;
  for (int k = 0; k < 2; k++) {
    int o = 0, tl = 0;
    TO[k * 9] = 0;
    for (int e = 0; e < 8; e++) {
      offs[k * 8 + e] = o;
      o += counts[k * 8 + e];
      tl += (counts[k * 8 + e] + BM - 1) / BM;
      TO[k * 9 + e + 1] = tl;
    }
  }
}

// ---------------- scatter tokens into expert segments ----------------
__global__ void moe_scatter(const int* __restrict__ tok_e, const float* __restrict__ tok_w,
                            int* __restrict__ meta, int* __restrict__ slot_token,
                            float* __restrict__ slot_w) {
  const int t = blockIdx.x * 256 + threadIdx.x;
  if (t >= N_TOK) return;
  const int* offs = meta + 16; int* rank = meta + 32;
#pragma unroll
  for (int k = 0; k < 2; k++) {
    const int e = tok_e[t * 2 + k];
    const int p = offs[k * 8 + e] + atomicAdd(&rank[k * 8 + e], 1);
    slot_token[k * N_TOK + p] = t;
    slot_w[k * N_TOK + p] = tok_w[t * 2 + k];
  }
}

// ---------------- x fp32 -> bf16 ----------------
__global__ __launch_bounds__(256) void moe_cvt_x(const float* __restrict__ x,
                                                 unsigned short* __restrict__ xb) {
  const long i = ((long)blockIdx.x * 256 + threadIdx.x) * 8;
  const float4 a = *(const float4*)(x + i);
  const float4 b = *(const float4*)(x + i + 4);
  uint4 o;
  o.x = (unsigned)f2bf(a.x) | ((unsigned)f2bf(a.y) << 16);
  o.y = (unsigned)f2bf(a.z) | ((unsigned)f2bf(a.w) << 16);
  o.z = (unsigned)f2bf(b.x) | ((unsigned)f2bf(b.y) << 16);
  o.w = (unsigned)f2bf(b.z) | ((unsigned)f2bf(b.w) << 16);
  *(uint4*)(xb + i) = o;
}

// ---------------- weight transpose + fp32->bf16 (24 x 1024x1024) ----------------
__global__ __launch_bounds__(256) void moe_tw(const float* __restrict__ W1,
                                              const float* __restrict__ Wg,
                                              const float* __restrict__ W2,
                                              unsigned short* __restrict__ w1b,
                                              unsigned short* __restrict__ wgb,
                                              unsigned short* __restrict__ w2b) {
  const int z = blockIdx.z;
  const float* src; unsigned short* dst;
  if (z < 8)       { src = W1 + (long)z * 1048576;        dst = w1b + (long)z * 1048576; }
  else if (z < 16) { src = Wg + (long)(z - 8) * 1048576;  dst = wgb + (long)(z - 8) * 1048576; }
  else             { src = W2 + (long)(z - 16) * 1048576; dst = w2b + (long)(z - 16) * 1048576; }
  __shared__ float tbuf[64][65];
  const int tx = threadIdx.x & 63, ty = threadIdx.x >> 6;
  const int r0 = blockIdx.y * 64, c0 = blockIdx.x * 64;
#pragma unroll
  for (int j = 0; j < 64; j += 4)
    tbuf[ty + j][tx] = src[(long)(r0 + ty + j) * 1024 + c0 + tx];
  __syncthreads();
#pragma unroll
  for (int j = 0; j < 64; j += 4)
    dst[(long)(c0 + ty + j) * 1024 + r0 + tx] = f2bf(tbuf[tx][ty + j]);
}

// ---------------- phase 1: act = silu(x W1 + b1) * (x Wg + bg) ----------------
__global__ __launch_bounds__(256, 2) void moe_phase1(
    const unsigned short* __restrict__ xb, const unsigned short* __restrict__ w1b,
    const unsigned short* __restrict__ wgb, const float* __restrict__ b1,
    const float* __restrict__ bg, unsigned short* __restrict__ act,
    const int* __restrict__ slot_token, const int* __restrict__ meta) {
  const int kpl = blockIdx.z;
  const int* counts = meta;
  const int* offs = meta + 16;
  const int* TO = meta + 48 + kpl * 9;
  const int mt = blockIdx.x;
  if (mt >= TO[8]) return;
  int e = 0;
#pragma unroll
  for (int q = 1; q < 8; q++) if (mt >= TO[q]) e = q;
  const int seg_start = offs[kpl * 8 + e];
  const int seg_n = counts[kpl * 8 + e];
  const int m0 = seg_start + (mt - TO[e]) * BM;
  const int rows_valid = min(BM, seg_start + seg_n - m0);
  const int nb = blockIdx.y * BN;
  const int tid = threadIdx.x, wid = tid >> 6, lane = tid & 63;
  const int wm = wid >> 1, wn = wid & 1;
  const int lane15 = lane & 15, lq = lane >> 4;

  __shared__ __align__(16) char lds[49152];  // A:0  B1:16K  Bg:32K

  const int l8 = lane >> 3, ch = lane & 7;
  long a_byte[4], b_byte[4];
#pragma unroll
  for (int i = 0; i < 4; i++) {
    const int r = wid * 32 + i * 8 + l8;
    const int rr = min(r, rows_valid - 1);
    const int tok = slot_token[kpl * N_TOK + m0 + rr];
    const int chs = ch ^ (r & 7);
    a_byte[i] = ((long)tok * CD + chs * 8) * 2;
    b_byte[i] = ((long)(e * ID + nb + r) * CD + chs * 8) * 2;
  }
  f32x4 acc_h[4][4], acc_g[4][4];
#pragma unroll
  for (int mi = 0; mi < 4; mi++)
#pragma unroll
    for (int ni = 0; ni < 4; ni++) { acc_h[mi][ni] = 0.f; acc_g[mi][ni] = 0.f; }

  for (int kb = 0; kb < CD; kb += BK) {
#pragma unroll
    for (int i = 0; i < 4; i++) {
      __builtin_amdgcn_global_load_lds(
          (const AS1 void*)((const char*)xb + a_byte[i]),
          (AS3 void*)(lds + (wid * 32 + i * 8) * 128), 16, 0, 0);
      a_byte[i] += 128;
    }
#pragma unroll
    for (int i = 0; i < 4; i++) {
      __builtin_amdgcn_global_load_lds(
          (const AS1 void*)((const char*)w1b + b_byte[i]),
          (AS3 void*)(lds + 16384 + (wid * 32 + i * 8) * 128), 16, 0, 0);
      __builtin_amdgcn_global_load_lds(
          (const AS1 void*)((const char*)wgb + b_byte[i]),
          (AS3 void*)(lds + 32768 + (wid * 32 + i * 8) * 128), 16, 0, 0);
      b_byte[i] += 128;
    }
    __syncthreads();
#pragma unroll
    for (int ks = 0; ks < 2; ks++) {
      bf16x8 af[4], bf1[4], bfg[4];
#pragma unroll
      for (int mi = 0; mi < 4; mi++) {
        const int row = wm * 64 + mi * 16 + lane15;
        const int byt = row * 128 + ((ks * 64 + lq * 16) ^ ((row & 7) << 4));
        af[mi] = *(const bf16x8*)(lds + byt);
      }
#pragma unroll
      for (int ni = 0; ni < 4; ni++) {
        const int row = wn * 64 + ni * 16 + lane15;
        const int byt = row * 128 + ((ks * 64 + lq * 16) ^ ((row & 7) << 4));
        bf1[ni] = *(const bf16x8*)(lds + 16384 + byt);
        bfg[ni] = *(const bf16x8*)(lds + 32768 + byt);
      }
#pragma unroll
      for (int mi = 0; mi < 4; mi++)
#pragma unroll
        for (int ni = 0; ni < 4; ni++) {
          acc_h[mi][ni] = __builtin_amdgcn_mfma_f32_16x16x32_bf16(af[mi], bf1[ni], acc_h[mi][ni], 0, 0, 0);
          acc_g[mi][ni] = __builtin_amdgcn_mfma_f32_16x16x32_bf16(af[mi], bfg[ni], acc_g[mi][ni], 0, 0, 0);
        }
    }
    __syncthreads();
  }

  // epilogue: silu(h)*g -> bf16, repack through LDS for coalesced store
  unsigned short* rp = (unsigned short*)lds;
#pragma unroll
  for (int mi = 0; mi < 4; mi++) {
#pragma unroll
    for (int ni = 0; ni < 4; ni++) {
      const int colLoc = wn * 64 + ni * 16 + lane15;
      const float bb1 = b1[e * ID + nb + colLoc];
      const float bbg = bg[e * ID + nb + colLoc];
#pragma unroll
      for (int j = 0; j < 4; j++) {
        const int row = wm * 64 + mi * 16 + lq * 4 + j;
        const float h = acc_h[mi][ni][j] + bb1;
        const float g = acc_g[mi][ni][j] + bbg;
        const float sv = h / (1.f + __expf(-h));
        rp[row * 128 + colLoc] = f2bf(sv * g);
      }
    }
  }
  __syncthreads();
  const long base = ((long)(kpl * N_TOK + m0)) * ID + nb;
#pragma unroll
  for (int it = 0; it < 8; it++) {
    const int chunk = it * 256 + tid;
    const int row = chunk >> 4;
    const int cc = (chunk & 15) * 8;
    if (row < rows_valid)
      *(uint4*)(act + base + (long)row * ID + cc) = *(const uint4*)(rp + row * 128 + cc);
  }
}

// ---------------- phase 2: out (=/+=) w * (act W2 + b2) ----------------
__global__ __launch_bounds__(256, 2) void moe_phase2(
    const unsigned short* __restrict__ act, const unsigned short* __restrict__ w2b,
    const float* __restrict__ b2, const int* __restrict__ slot_token,
    const float* __restrict__ slot_w, float* __restrict__ out,
    const int* __restrict__ meta, const int kpl) {
  const int* counts = meta;
  const int* offs = meta + 16;
  const int* TO = meta + 48 + kpl * 9;
  const int mt = blockIdx.x;
  if (mt >= TO[8]) return;
  int e = 0;
#pragma unroll
  for (int q = 1; q < 8; q++) if (mt >= TO[q]) e = q;
  const int seg_start = offs[kpl * 8 + e];
  const int seg_n = counts[kpl * 8 + e];
  const int m0 = seg_start + (mt - TO[e]) * BM;
  const int rows_valid = min(BM, seg_start + seg_n - m0);
  const int nb = blockIdx.y * BN;
  const int tid = threadIdx.x, wid = tid >> 6, lane = tid & 63;
  const int wm = wid >> 1, wn = wid & 1;
  const int lane15 = lane & 15, lq = lane >> 4;

  __shared__ __align__(16) char lds[32768];  // A:0  B:16K

  const int l8 = lane >> 3, ch = lane & 7;
  long a_byte[4], b_byte[4];
#pragma unroll
  for (int i = 0; i < 4; i++) {
    const int r = wid * 32 + i * 8 + l8;
    const int rr = min(r, rows_valid - 1);
    const int chs = ch ^ (r & 7);
    a_byte[i] = ((long)(kpl * N_TOK + m0 + rr) * ID + chs * 8) * 2;
    b_byte[i] = ((long)(e * CD + nb + r) * ID + chs * 8) * 2;
  }
  f32x4 acc[4][4];
#pragma unroll
  for (int mi = 0; mi < 4; mi++)
#pragma unroll
    for (int ni = 0; ni < 4; ni++) acc[mi][ni] = 0.f;

  for (int kb = 0; kb < ID; kb += BK) {
#pragma unroll
    for (int i = 0; i < 4; i++) {
      __builtin_amdgcn_global_load_lds(
          (const AS1 void*)((const char*)act + a_byte[i]),
          (AS3 void*)(lds + (wid * 32 + i * 8) * 128), 16, 0, 0);
      a_byte[i] += 128;
    }
#pragma unroll
    for (int i = 0; i < 4; i++) {
      __builtin_amdgcn_global_load_lds(
          (const AS1 void*)((const char*)w2b + b_byte[i]),
          (AS3 void*)(lds + 16384 + (wid * 32 + i * 8) * 128), 16, 0, 0);
      b_byte[i] += 128;
    }
    __syncthreads();
#pragma unroll
    for (int ks = 0; ks < 2; ks++) {
      bf16x8 af[4], bf2[4];
#pragma unroll
      for (int mi = 0; mi < 4; mi++) {
        const int row = wm * 64 + mi * 16 + lane15;
        const int byt = row * 128 + ((ks * 64 + lq * 16) ^ ((row & 7) << 4));
        af[mi] = *(const bf16x8*)(lds + byt);
      }
#pragma unroll
      for (int ni = 0; ni < 4; ni++) {
        const int row = wn * 64 + ni * 16 + lane15;
        const int byt = row * 128 + ((ks * 64 + lq * 16) ^ ((row & 7) << 4));
        bf2[ni] = *(const bf16x8*)(lds + 16384 + byt);
      }
#pragma unroll
      for (int mi = 0; mi < 4; mi++)
#pragma unroll
        for (int ni = 0; ni < 4; ni++)
          acc[mi][ni] = __builtin_amdgcn_mfma_f32_16x16x32_bf16(af[mi], bf2[ni], acc[mi][ni], 0, 0, 0);
    }
    __syncthreads();
  }

#pragma unroll
  for (int mi = 0; mi < 4; mi++) {
    int t4[4]; float w4[4]; int rv[4];
#pragma unroll
    for (int j = 0; j < 4; j++) {
      const int r = wm * 64 + mi * 16 + lq * 4 + j;
      rv[j] = (r < rows_valid);
      const int p = kpl * N_TOK + m0 + min(r, rows_valid - 1);
      t4[j] = slot_token[p];
      w4[j] = slot_w[p];
    }
#pragma unroll
    for (int ni = 0; ni < 4; ni++) {
      const int col = nb + wn * 64 + ni * 16 + lane15;
      const float bb = b2[e * CD + col];
#pragma unroll
      for (int j = 0; j < 4; j++) {
        if (rv[j]) {
          const long o = (long)t4[j] * CD + col;
          const float v = (acc[mi][ni][j] + bb) * w4[j];
          if (kpl == 0) out[o] = v;
          else out[o] += v;
        }
      }
    }
  }
}

extern "C" void kernel_launch(void* const* d_in, const int* in_sizes, int n_in,
                              void* d_out, int out_size, void* d_ws, size_t ws_size,
                              hipStream_t stream) {
  const float* x  = (const float*)d_in[0];
  const float* Wr = (const float*)d_in[1];
  const float* br = (const float*)d_in[2];
  const float* W1 = (const float*)d_in[3];
  const float* b1 = (const float*)d_in[4];
  const float* Wg = (const float*)d_in[5];
  const float* bg = (const float*)d_in[6];
  const float* W2 = (const float*)d_in[7];
  const float* b2 = (const float*)d_in[8];
  float* out = (float*)d_out;
  char* ws = (char*)d_ws;

  unsigned short* xb  = (unsigned short*)(ws + XB_OFF);
  unsigned short* w1b = (unsigned short*)(ws + W1B_OFF);
  unsigned short* wgb = (unsigned short*)(ws + WGB_OFF);
  unsigned short* w2b = (unsigned short*)(ws + W2B_OFF);
  unsigned short* act = (unsigned short*)(ws + ACT_OFF);
  int*   slot_token = (int*)(ws + ST_OFF);
  float* slot_w     = (float*)(ws + SW_OFF);
  int*   tok_e      = (int*)(ws + TE_OFF);
  float* tok_w      = (float*)(ws + TW_OFF);
  int*   meta       = (int*)(ws + META_OFF);

  hipMemsetAsync(meta, 0, 512, stream);
  moe_router<<<N_TOK / 4, 256, 0, stream>>>(x, Wr, br, tok_e, tok_w, meta);
  moe_offsets<<<1, 1, 0, stream>>>(meta);
  moe_scatter<<<N_TOK / 256, 256, 0, stream>>>(tok_e, tok_w, meta, slot_token, slot_w);
  moe_cvt_x<<<(N_TOK * CD) / (256 * 8), 256, 0, stream>>>(x, xb);
  moe_tw<<<dim3(16, 16, 24), 256, 0, stream>>>(W1, Wg, W2, w1b, wgb, w2b);
  moe_phase1<<<dim3(MAXMT, ID / BN, 2), 256, 0, stream>>>(xb, w1b, wgb, b1, bg, act, slot_token, meta);
  moe_phase2<<<dim3(MAXMT, CD / BN), 256, 0, stream>>>(act, w2b, b2, slot_token, slot_w, out, meta, 0);
  moe_phase2<<<dim3(MAXMT, CD / BN), 256, 0, stream>>>(act, w2b, b2, slot_token, slot_w, out, meta, 1);
}

// Round 2
// 484.946 us; speedup vs baseline: 1.0205x; 1.0205x over previous
//
#include <hip/hip_runtime.h>

#define AS1 __attribute__((address_space(1)))
#define AS3 __attribute__((address_space(3)))

typedef __attribute__((ext_vector_type(8))) short bf16x8;
typedef __attribute__((ext_vector_type(4))) float f32x4;

#define N_TOK 8192
#define CD 1024
#define ID 1024
#define BM 128
#define BN 128
#define BK 64
#define MAXMT 72

// ---- workspace layout (bytes) ----
#define XB_OFF   0LL            // x bf16 [N,C]                16MB
#define W1B_OFF  16777216LL     // W1^T bf16 [E][I][C]         16MB
#define WGB_OFF  33554432LL     // Wg^T bf16 [E][I][C]         16MB
#define W2B_OFF  50331648LL     // W2^T bf16 [E][C][I]         16MB
#define ACT_OFF  67108864LL     // act bf16 [2N][I]            32MB
#define ST_OFF   100663296LL    // slot_token int [2N]
#define SW_OFF   100728832LL    // slot_w float [2N]
#define TE_OFF   100794368LL    // tok_e int [N*2]
#define TW_OFF   100859904LL    // tok_w float [N*2]
#define META_OFF 100925440LL    // counts[16] offs[16] rank[16] TO[2][9]

static __device__ __forceinline__ unsigned short f2bf(float f) {
  union { float f; unsigned u; } v; v.f = f;
  unsigned r = v.u + 0x7fffu + ((v.u >> 16) & 1u);
  return (unsigned short)(r >> 16);
}

// ---------------- fused router + x fp32->bf16 ----------------
// One block per token. Thread tid owns channels [4*tid, 4*tid+4): coalesced
// float4 x load, inline bf16 convert+store, 128B contiguous Wr slice
// (Wr read once per BLOCK, not once per wave per iteration).
__global__ __launch_bounds__(256) void moe_router_cvt(
    const float* __restrict__ x, const float* __restrict__ Wr,
    const float* __restrict__ br, unsigned short* __restrict__ xb,
    int* __restrict__ tok_e, float* __restrict__ tok_w, int* __restrict__ meta) {
  const int t = blockIdx.x;
  const int tid = threadIdx.x;
  const int wid = tid >> 6, lane = tid & 63;
  const int c0 = tid * 4;
  const long xoff = (long)t * CD + c0;
  const float4 xv = *(const float4*)(x + xoff);
  uint2 ob;
  ob.x = (unsigned)f2bf(xv.x) | ((unsigned)f2bf(xv.y) << 16);
  ob.y = (unsigned)f2bf(xv.z) | ((unsigned)f2bf(xv.w) << 16);
  *(uint2*)(xb + xoff) = ob;

  float acc[8];
#pragma unroll
  for (int e = 0; e < 8; e++) acc[e] = 0.f;
  const float* wr = Wr + (long)c0 * 8;
  const float xj[4] = {xv.x, xv.y, xv.z, xv.w};
#pragma unroll
  for (int j = 0; j < 4; j++) {
    const float4 w0 = *(const float4*)(wr + j * 8);
    const float4 w1 = *(const float4*)(wr + j * 8 + 4);
    acc[0] += xj[j] * w0.x; acc[1] += xj[j] * w0.y;
    acc[2] += xj[j] * w0.z; acc[3] += xj[j] * w0.w;
    acc[4] += xj[j] * w1.x; acc[5] += xj[j] * w1.y;
    acc[6] += xj[j] * w1.z; acc[7] += xj[j] * w1.w;
  }
#pragma unroll
  for (int e = 0; e < 8; e++)
#pragma unroll
    for (int off = 32; off; off >>= 1) acc[e] += __shfl_xor(acc[e], off);

  __shared__ float red[4][8];
  if (lane == 0) {
#pragma unroll
    for (int e = 0; e < 8; e++) red[wid][e] = acc[e];
  }
  __syncthreads();
  if (tid == 0) {
    float lg[8];
#pragma unroll
    for (int e = 0; e < 8; e++)
      lg[e] = red[0][e] + red[1][e] + red[2][e] + red[3][e] + br[e];
    int i1 = 0; float m1v = lg[0];
#pragma unroll
    for (int e = 1; e < 8; e++) if (lg[e] > m1v) { m1v = lg[e]; i1 = e; }
    int i2 = -1; float m2v = -1e30f;
#pragma unroll
    for (int e = 0; e < 8; e++) if (e != i1 && lg[e] > m2v) { m2v = lg[e]; i2 = e; }
    float s = 0.f;
#pragma unroll
    for (int e = 0; e < 8; e++) s += __expf(lg[e] - m1v);
    const float w1v = 1.f / s;
    const float w2v = __expf(m2v - m1v) / s;
    tok_e[2 * t] = i1; tok_e[2 * t + 1] = i2;
    tok_w[2 * t] = w1v; tok_w[2 * t + 1] = w2v;
    atomicAdd(&meta[i1], 1);
    atomicAdd(&meta[8 + i2], 1);
  }
}

// ---------------- offsets + tile offsets (1 thread) ----------------
__global__ void moe_offsets(int* __restrict__ meta) {
  if (threadIdx.x != 0 || blockIdx.x != 0) return;
  int* counts = meta; int* offs = meta + 16; int* TO = meta + 48;
  for (int k = 0; k < 2; k++) {
    int o = 0, tl = 0;
    TO[k * 9] = 0;
    for (int e = 0; e < 8; e++) {
      offs[k * 8 + e] = o;
      o += counts[k * 8 + e];
      tl += (counts[k * 8 + e] + BM - 1) / BM;
      TO[k * 9 + e + 1] = tl;
    }
  }
}

// ---------------- scatter tokens into expert segments ----------------
__global__ void moe_scatter(const int* __restrict__ tok_e, const float* __restrict__ tok_w,
                            int* __restrict__ meta, int* __restrict__ slot_token,
                            float* __restrict__ slot_w) {
  const int t = blockIdx.x * 256 + threadIdx.x;
  if (t >= N_TOK) return;
  const int* offs = meta + 16; int* rank = meta + 32;
#pragma unroll
  for (int k = 0; k < 2; k++) {
    const int e = tok_e[t * 2 + k];
    const int p = offs[k * 8 + e] + atomicAdd(&rank[k * 8 + e], 1);
    slot_token[k * N_TOK + p] = t;
    slot_w[k * N_TOK + p] = tok_w[t * 2 + k];
  }
}

// ---------------- weight transpose + fp32->bf16 (24 x 1024x1024) ----------------
__global__ __launch_bounds__(256) void moe_tw(const float* __restrict__ W1,
                                              const float* __restrict__ Wg,
                                              const float* __restrict__ W2,
                                              unsigned short* __restrict__ w1b,
                                              unsigned short* __restrict__ wgb,
                                              unsigned short* __restrict__ w2b) {
  const int z = blockIdx.z;
  const float* src; unsigned short* dst;
  if (z < 8)       { src = W1 + (long)z * 1048576;        dst = w1b + (long)z * 1048576; }
  else if (z < 16) { src = Wg + (long)(z - 8) * 1048576;  dst = wgb + (long)(z - 8) * 1048576; }
  else             { src = W2 + (long)(z - 16) * 1048576; dst = w2b + (long)(z - 16) * 1048576; }
  __shared__ float tbuf[64][65];
  const int tx = threadIdx.x & 63, ty = threadIdx.x >> 6;
  const int r0 = blockIdx.y * 64, c0 = blockIdx.x * 64;
#pragma unroll
  for (int j = 0; j < 64; j += 4)
    tbuf[ty + j][tx] = src[(long)(r0 + ty + j) * 1024 + c0 + tx];
  __syncthreads();
#pragma unroll
  for (int j = 0; j < 64; j += 4)
    dst[(long)(c0 + ty + j) * 1024 + r0 + tx] = f2bf(tbuf[tx][ty + j]);
}

// ---------------- phase 1: act = silu(x W1 + b1) * (x Wg + bg) ----------------
__global__ __launch_bounds__(256, 2) void moe_phase1(
    const unsigned short* __restrict__ xb, const unsigned short* __restrict__ w1b,
    const unsigned short* __restrict__ wgb, const float* __restrict__ b1,
    const float* __restrict__ bg, unsigned short* __restrict__ act,
    const int* __restrict__ slot_token, const int* __restrict__ meta) {
  const int kpl = blockIdx.z;
  const int* counts = meta;
  const int* offs = meta + 16;
  const int* TO = meta + 48 + kpl * 9;
  const int mt = blockIdx.x;
  if (mt >= TO[8]) return;
  int e = 0;
#pragma unroll
  for (int q = 1; q < 8; q++) if (mt >= TO[q]) e = q;
  const int seg_start = offs[kpl * 8 + e];
  const int seg_n = counts[kpl * 8 + e];
  const int m0 = seg_start + (mt - TO[e]) * BM;
  const int rows_valid = min(BM, seg_start + seg_n - m0);
  const int nb = blockIdx.y * BN;
  const int tid = threadIdx.x, wid = tid >> 6, lane = tid & 63;
  const int wm = wid >> 1, wn = wid & 1;
  const int lane15 = lane & 15, lq = lane >> 4;

  __shared__ __align__(16) char lds[49152];  // A:0  B1:16K  Bg:32K

  const int l8 = lane >> 3, ch = lane & 7;
  long a_byte[4], b_byte[4];
#pragma unroll
  for (int i = 0; i < 4; i++) {
    const int r = wid * 32 + i * 8 + l8;
    const int rr = min(r, rows_valid - 1);
    const int tok = slot_token[kpl * N_TOK + m0 + rr];
    const int chs = ch ^ (r & 7);
    a_byte[i] = ((long)tok * CD + chs * 8) * 2;
    b_byte[i] = ((long)(e * ID + nb + r) * CD + chs * 8) * 2;
  }
  f32x4 acc_h[4][4], acc_g[4][4];
#pragma unroll
  for (int mi = 0; mi < 4; mi++)
#pragma unroll
    for (int ni = 0; ni < 4; ni++) { acc_h[mi][ni] = 0.f; acc_g[mi][ni] = 0.f; }

  for (int kb = 0; kb < CD; kb += BK) {
#pragma unroll
    for (int i = 0; i < 4; i++) {
      __builtin_amdgcn_global_load_lds(
          (const AS1 void*)((const char*)xb + a_byte[i]),
          (AS3 void*)(lds + (wid * 32 + i * 8) * 128), 16, 0, 0);
      a_byte[i] += 128;
    }
#pragma unroll
    for (int i = 0; i < 4; i++) {
      __builtin_amdgcn_global_load_lds(
          (const AS1 void*)((const char*)w1b + b_byte[i]),
          (AS3 void*)(lds + 16384 + (wid * 32 + i * 8) * 128), 16, 0, 0);
      __builtin_amdgcn_global_load_lds(
          (const AS1 void*)((const char*)wgb + b_byte[i]),
          (AS3 void*)(lds + 32768 + (wid * 32 + i * 8) * 128), 16, 0, 0);
      b_byte[i] += 128;
    }
    __syncthreads();
#pragma unroll
    for (int ks = 0; ks < 2; ks++) {
      bf16x8 af[4], bf1[4], bfg[4];
#pragma unroll
      for (int mi = 0; mi < 4; mi++) {
        const int row = wm * 64 + mi * 16 + lane15;
        const int byt = row * 128 + ((ks * 64 + lq * 16) ^ ((row & 7) << 4));
        af[mi] = *(const bf16x8*)(lds + byt);
      }
#pragma unroll
      for (int ni = 0; ni < 4; ni++) {
        const int row = wn * 64 + ni * 16 + lane15;
        const int byt = row * 128 + ((ks * 64 + lq * 16) ^ ((row & 7) << 4));
        bf1[ni] = *(const bf16x8*)(lds + 16384 + byt);
        bfg[ni] = *(const bf16x8*)(lds + 32768 + byt);
      }
#pragma unroll
      for (int mi = 0; mi < 4; mi++)
#pragma unroll
        for (int ni = 0; ni < 4; ni++) {
          acc_h[mi][ni] = __builtin_amdgcn_mfma_f32_16x16x32_bf16(af[mi], bf1[ni], acc_h[mi][ni], 0, 0, 0);
          acc_g[mi][ni] = __builtin_amdgcn_mfma_f32_16x16x32_bf16(af[mi], bfg[ni], acc_g[mi][ni], 0, 0, 0);
        }
    }
    __syncthreads();
  }

  // epilogue: silu(h)*g -> bf16, repack through LDS for coalesced store
  unsigned short* rp = (unsigned short*)lds;
#pragma unroll
  for (int mi = 0; mi < 4; mi++) {
#pragma unroll
    for (int ni = 0; ni < 4; ni++) {
      const int colLoc = wn * 64 + ni * 16 + lane15;
      const float bb1 = b1[e * ID + nb + colLoc];
      const float bbg = bg[e * ID + nb + colLoc];
#pragma unroll
      for (int j = 0; j < 4; j++) {
        const int row = wm * 64 + mi * 16 + lq * 4 + j;
        const float h = acc_h[mi][ni][j] + bb1;
        const float g = acc_g[mi][ni][j] + bbg;
        const float sv = h / (1.f + __expf(-h));
        rp[row * 128 + colLoc] = f2bf(sv * g);
      }
    }
  }
  __syncthreads();
  const long base = ((long)(kpl * N_TOK + m0)) * ID + nb;
#pragma unroll
  for (int it = 0; it < 8; it++) {
    const int chunk = it * 256 + tid;
    const int row = chunk >> 4;
    const int cc = (chunk & 15) * 8;
    if (row < rows_valid)
      *(uint4*)(act + base + (long)row * ID + cc) = *(const uint4*)(rp + row * 128 + cc);
  }
}

// ---------------- phase 2: out (=/+=) w * (act W2 + b2) ----------------
__global__ __launch_bounds__(256, 2) void moe_phase2(
    const unsigned short* __restrict__ act, const unsigned short* __restrict__ w2b,
    const float* __restrict__ b2, const int* __restrict__ slot_token,
    const float* __restrict__ slot_w, float* __restrict__ out,
    const int* __restrict__ meta, const int kpl) {
  const int* counts = meta;
  const int* offs = meta + 16;
  const int* TO = meta + 48 + kpl * 9;
  const int mt = blockIdx.x;
  if (mt >= TO[8]) return;
  int e = 0;
#pragma unroll
  for (int q = 1; q < 8; q++) if (mt >= TO[q]) e = q;
  const int seg_start = offs[kpl * 8 + e];
  const int seg_n = counts[kpl * 8 + e];
  const int m0 = seg_start + (mt - TO[e]) * BM;
  const int rows_valid = min(BM, seg_start + seg_n - m0);
  const int nb = blockIdx.y * BN;
  const int tid = threadIdx.x, wid = tid >> 6, lane = tid & 63;
  const int wm = wid >> 1, wn = wid & 1;
  const int lane15 = lane & 15, lq = lane >> 4;

  __shared__ __align__(16) char lds[32768];  // A:0  B:16K

  const int l8 = lane >> 3, ch = lane & 7;
  long a_byte[4], b_byte[4];
#pragma unroll
  for (int i = 0; i < 4; i++) {
    const int r = wid * 32 + i * 8 + l8;
    const int rr = min(r, rows_valid - 1);
    const int chs = ch ^ (r & 7);
    a_byte[i] = ((long)(kpl * N_TOK + m0 + rr) * ID + chs * 8) * 2;
    b_byte[i] = ((long)(e * CD + nb + r) * ID + chs * 8) * 2;
  }
  f32x4 acc[4][4];
#pragma unroll
  for (int mi = 0; mi < 4; mi++)
#pragma unroll
    for (int ni = 0; ni < 4; ni++) acc[mi][ni] = 0.f;

  for (int kb = 0; kb < ID; kb += BK) {
#pragma unroll
    for (int i = 0; i < 4; i++) {
      __builtin_amdgcn_global_load_lds(
          (const AS1 void*)((const char*)act + a_byte[i]),
          (AS3 void*)(lds + (wid * 32 + i * 8) * 128), 16, 0, 0);
      a_byte[i] += 128;
    }
#pragma unroll
    for (int i = 0; i < 4; i++) {
      __builtin_amdgcn_global_load_lds(
          (const AS1 void*)((const char*)w2b + b_byte[i]),
          (AS3 void*)(lds + 16384 + (wid * 32 + i * 8) * 128), 16, 0, 0);
      b_byte[i] += 128;
    }
    __syncthreads();
#pragma unroll
    for (int ks = 0; ks < 2; ks++) {
      bf16x8 af[4], bf2[4];
#pragma unroll
      for (int mi = 0; mi < 4; mi++) {
        const int row = wm * 64 + mi * 16 + lane15;
        const int byt = row * 128 + ((ks * 64 + lq * 16) ^ ((row & 7) << 4));
        af[mi] = *(const bf16x8*)(lds + byt);
      }
#pragma unroll
      for (int ni = 0; ni < 4; ni++) {
        const int row = wn * 64 + ni * 16 + lane15;
        const int byt = row * 128 + ((ks * 64 + lq * 16) ^ ((row & 7) << 4));
        bf2[ni] = *(const bf16x8*)(lds + 16384 + byt);
      }
#pragma unroll
      for (int mi = 0; mi < 4; mi++)
#pragma unroll
        for (int ni = 0; ni < 4; ni++)
          acc[mi][ni] = __builtin_amdgcn_mfma_f32_16x16x32_bf16(af[mi], bf2[ni], acc[mi][ni], 0, 0, 0);
    }
    __syncthreads();
  }

#pragma unroll
  for (int mi = 0; mi < 4; mi++) {
    int t4[4]; float w4[4]; int rv[4];
#pragma unroll
    for (int j = 0; j < 4; j++) {
      const int r = wm * 64 + mi * 16 + lq * 4 + j;
      rv[j] = (r < rows_valid);
      const int p = kpl * N_TOK + m0 + min(r, rows_valid - 1);
      t4[j] = slot_token[p];
      w4[j] = slot_w[p];
    }
#pragma unroll
    for (int ni = 0; ni < 4; ni++) {
      const int col = nb + wn * 64 + ni * 16 + lane15;
      const float bb = b2[e * CD + col];
#pragma unroll
      for (int j = 0; j < 4; j++) {
        if (rv[j]) {
          const long o = (long)t4[j] * CD + col;
          const float v = (acc[mi][ni][j] + bb) * w4[j];
          if (kpl == 0) out[o] = v;
          else out[o] += v;
        }
      }
    }
  }
}

extern "C" void kernel_launch(void* const* d_in, const int* in_sizes, int n_in,
                              void* d_out, int out_size, void* d_ws, size_t ws_size,
                              hipStream_t stream) {
  const float* x  = (const float*)d_in[0];
  const float* Wr = (const float*)d_in[1];
  const float* br = (const float*)d_in[2];
  const float* W1 = (const float*)d_in[3];
  const float* b1 = (const float*)d_in[4];
  const float* Wg = (const float*)d_in[5];
  const float* bg = (const float*)d_in[6];
  const float* W2 = (const float*)d_in[7];
  const float* b2 = (const float*)d_in[8];
  float* out = (float*)d_out;
  char* ws = (char*)d_ws;

  unsigned short* xb  = (unsigned short*)(ws + XB_OFF);
  unsigned short* w1b = (unsigned short*)(ws + W1B_OFF);
  unsigned short* wgb = (unsigned short*)(ws + WGB_OFF);
  unsigned short* w2b = (unsigned short*)(ws + W2B_OFF);
  unsigned short* act = (unsigned short*)(ws + ACT_OFF);
  int*   slot_token = (int*)(ws + ST_OFF);
  float* slot_w     = (float*)(ws + SW_OFF);
  int*   tok_e      = (int*)(ws + TE_OFF);
  float* tok_w      = (float*)(ws + TW_OFF);
  int*   meta       = (int*)(ws + META_OFF);

  hipMemsetAsync(meta, 0, 512, stream);
  moe_router_cvt<<<N_TOK, 256, 0, stream>>>(x, Wr, br, xb, tok_e, tok_w, meta);
  moe_offsets<<<1, 1, 0, stream>>>(meta);
  moe_scatter<<<N_TOK / 256, 256, 0, stream>>>(tok_e, tok_w, meta, slot_token, slot_w);
  moe_tw<<<dim3(16, 16, 24), 256, 0, stream>>>(W1, Wg, W2, w1b, wgb, w2b);
  moe_phase1<<<dim3(MAXMT, ID / BN, 2), 256, 0, stream>>>(xb, w1b, wgb, b1, bg, act, slot_token, meta);
  moe_phase2<<<dim3(MAXMT, CD / BN), 256, 0, stream>>>(act, w2b, b2, slot_token, slot_w, out, meta, 0);
  moe_phase2<<<dim3(MAXMT, CD / BN), 256, 0, stream>>>(act, w2b, b2, slot_token, slot_w, out, meta, 1);
}

// Round 3
// 482.187 us; speedup vs baseline: 1.0263x; 1.0057x over previous
//
#include <hip/hip_runtime.h>

#define AS1 __attribute__((address_space(1)))
#define AS3 __attribute__((address_space(3)))

typedef __attribute__((ext_vector_type(8))) short bf16x8;
typedef __attribute__((ext_vector_type(4))) float f32x4;

#define N_TOK 8192
#define CD 1024
#define ID 1024
#define BM 128
#define BN 128
#define BK 64
#define MAXMT 72

// ---- workspace layout (bytes) ----
#define XB_OFF   0LL            // x bf16 [N,C]                16MB
#define W1B_OFF  16777216LL     // W1^T bf16 [E][I][C]         16MB
#define WGB_OFF  33554432LL     // Wg^T bf16 [E][I][C]         16MB
#define W2B_OFF  50331648LL     // W2^T bf16 [E][C][I]         16MB
#define ACT_OFF  67108864LL     // act bf16 [2N][I]            32MB
#define ST_OFF   100663296LL    // slot_token int [2N]
#define SW_OFF   100728832LL    // slot_w float [2N]
#define TE_OFF   100794368LL    // tok_e int [N*2]
#define TW_OFF   100859904LL    // tok_w float [N*2]
#define META_OFF 100925440LL    // counts[16] offs[16] rank[16] TO[2][9]

static __device__ __forceinline__ unsigned short f2bf(float f) {
  union { float f; unsigned u; } v; v.f = f;
  unsigned r = v.u + 0x7fffu + ((v.u >> 16) & 1u);
  return (unsigned short)(r >> 16);
}

// ---------------- fused router + x fp32->bf16 ----------------
// One block per token. All Wr traffic is either coalesced (staging) or
// LDS-resident (padded [256][33] layout -> 2-way bank aliasing = free).
// Round-2 lesson: per-lane 128B-strided Wr gathers cost ~64 cache-line
// transactions per instruction; that (not bytes) was the 195us.
__global__ __launch_bounds__(256) void moe_router_cvt(
    const float* __restrict__ x, const float* __restrict__ Wr,
    const float* __restrict__ br, unsigned short* __restrict__ xb,
    int* __restrict__ tok_e, float* __restrict__ tok_w, int* __restrict__ meta) {
  const int t = blockIdx.x;
  const int tid = threadIdx.x;
  __shared__ float wr_s[256 * 33];   // Wr, rows of 32 floats padded to 33
  __shared__ float red[8 * 256];     // per-thread partials, [e][tid]
  __shared__ float lg_s[8];

  // ---- stage Wr coalesced: 8 x float4 global, 32 scalar LDS writes ----
#pragma unroll
  for (int k = 0; k < 8; k++) {
    const float4 w = *(const float4*)(Wr + (long)(k * 256 + tid) * 4);
    const int row = k * 32 + (tid >> 3);          // (a>>5) for a = 1024k+4tid
    const int col = (tid * 4) & 31;
    float* d = wr_s + row * 33 + col;
    d[0] = w.x; d[1] = w.y; d[2] = w.z; d[3] = w.w;
  }

  // ---- x load + bf16 convert/store (coalesced float4 / uint2) ----
  const int c0 = tid * 4;
  const long xoff = (long)t * CD + c0;
  const float4 xv = *(const float4*)(x + xoff);
  uint2 ob;
  ob.x = (unsigned)f2bf(xv.x) | ((unsigned)f2bf(xv.y) << 16);
  ob.y = (unsigned)f2bf(xv.z) | ((unsigned)f2bf(xv.w) << 16);
  *(uint2*)(xb + xoff) = ob;

  __syncthreads();

  // ---- partial logits: thread's 4 channels x 8 experts, Wr from LDS ----
  const float xj[4] = {xv.x, xv.y, xv.z, xv.w};
  float acc[8];
#pragma unroll
  for (int e = 0; e < 8; e++) acc[e] = 0.f;
  const float* wrow = wr_s + tid * 33;
#pragma unroll
  for (int j = 0; j < 4; j++)
#pragma unroll
    for (int e = 0; e < 8; e++)
      acc[e] += xj[j] * wrow[j * 8 + e];

  // ---- block reduce: LDS transpose + 32-lane shfl tree ----
#pragma unroll
  for (int e = 0; e < 8; e++) red[e * 256 + tid] = acc[e];
  __syncthreads();
  {
    const int e = tid >> 5, l = tid & 31;
    float s = 0.f;
#pragma unroll
    for (int k = 0; k < 8; k++) s += red[e * 256 + l + k * 32];
#pragma unroll
    for (int off = 16; off; off >>= 1) s += __shfl_xor(s, off);
    if (l == 0) lg_s[e] = s;
  }
  __syncthreads();

  if (tid == 0) {
    float lg[8];
#pragma unroll
    for (int e = 0; e < 8; e++) lg[e] = lg_s[e] + br[e];
    int i1 = 0; float m1v = lg[0];
#pragma unroll
    for (int e = 1; e < 8; e++) if (lg[e] > m1v) { m1v = lg[e]; i1 = e; }
    int i2 = -1; float m2v = -1e30f;
#pragma unroll
    for (int e = 0; e < 8; e++) if (e != i1 && lg[e] > m2v) { m2v = lg[e]; i2 = e; }
    float s = 0.f;
#pragma unroll
    for (int e = 0; e < 8; e++) s += __expf(lg[e] - m1v);
    const float w1v = 1.f / s;
    const float w2v = __expf(m2v - m1v) / s;
    tok_e[2 * t] = i1; tok_e[2 * t + 1] = i2;
    tok_w[2 * t] = w1v; tok_w[2 * t + 1] = w2v;
    atomicAdd(&meta[i1], 1);
    atomicAdd(&meta[8 + i2], 1);
  }
}

// ---------------- offsets + tile offsets (1 thread) ----------------
__global__ void moe_offsets(int* __restrict__ meta) {
  if (threadIdx.x != 0 || blockIdx.x != 0) return;
  int* counts = meta; int* offs = meta + 16; int* TO = meta + 48;
  for (int k = 0; k < 2; k++) {
    int o = 0, tl = 0;
    TO[k * 9] = 0;
    for (int e = 0; e < 8; e++) {
      offs[k * 8 + e] = o;
      o += counts[k * 8 + e];
      tl += (counts[k * 8 + e] + BM - 1) / BM;
      TO[k * 9 + e + 1] = tl;
    }
  }
}

// ---------------- scatter tokens into expert segments ----------------
__global__ void moe_scatter(const int* __restrict__ tok_e, const float* __restrict__ tok_w,
                            int* __restrict__ meta, int* __restrict__ slot_token,
                            float* __restrict__ slot_w) {
  const int t = blockIdx.x * 256 + threadIdx.x;
  if (t >= N_TOK) return;
  const int* offs = meta + 16; int* rank = meta + 32;
#pragma unroll
  for (int k = 0; k < 2; k++) {
    const int e = tok_e[t * 2 + k];
    const int p = offs[k * 8 + e] + atomicAdd(&rank[k * 8 + e], 1);
    slot_token[k * N_TOK + p] = t;
    slot_w[k * N_TOK + p] = tok_w[t * 2 + k];
  }
}

// ---------------- weight transpose + fp32->bf16 (24 x 1024x1024) ----------------
__global__ __launch_bounds__(256) void moe_tw(const float* __restrict__ W1,
                                              const float* __restrict__ Wg,
                                              const float* __restrict__ W2,
                                              unsigned short* __restrict__ w1b,
                                              unsigned short* __restrict__ wgb,
                                              unsigned short* __restrict__ w2b) {
  const int z = blockIdx.z;
  const float* src; unsigned short* dst;
  if (z < 8)       { src = W1 + (long)z * 1048576;        dst = w1b + (long)z * 1048576; }
  else if (z < 16) { src = Wg + (long)(z - 8) * 1048576;  dst = wgb + (long)(z - 8) * 1048576; }
  else             { src = W2 + (long)(z - 16) * 1048576; dst = w2b + (long)(z - 16) * 1048576; }
  __shared__ float tbuf[64][65];
  const int tx = threadIdx.x & 63, ty = threadIdx.x >> 6;
  const int r0 = blockIdx.y * 64, c0 = blockIdx.x * 64;
#pragma unroll
  for (int j = 0; j < 64; j += 4)
    tbuf[ty + j][tx] = src[(long)(r0 + ty + j) * 1024 + c0 + tx];
  __syncthreads();
#pragma unroll
  for (int j = 0; j < 64; j += 4)
    dst[(long)(c0 + ty + j) * 1024 + r0 + tx] = f2bf(tbuf[tx][ty + j]);
}

// ---------------- phase 1: act = silu(x W1 + b1) * (x Wg + bg) ----------------
__global__ __launch_bounds__(256, 2) void moe_phase1(
    const unsigned short* __restrict__ xb, const unsigned short* __restrict__ w1b,
    const unsigned short* __restrict__ wgb, const float* __restrict__ b1,
    const float* __restrict__ bg, unsigned short* __restrict__ act,
    const int* __restrict__ slot_token, const int* __restrict__ meta) {
  const int kpl = blockIdx.z;
  const int* counts = meta;
  const int* offs = meta + 16;
  const int* TO = meta + 48 + kpl * 9;
  const int mt = blockIdx.x;
  if (mt >= TO[8]) return;
  int e = 0;
#pragma unroll
  for (int q = 1; q < 8; q++) if (mt >= TO[q]) e = q;
  const int seg_start = offs[kpl * 8 + e];
  const int seg_n = counts[kpl * 8 + e];
  const int m0 = seg_start + (mt - TO[e]) * BM;
  const int rows_valid = min(BM, seg_start + seg_n - m0);
  const int nb = blockIdx.y * BN;
  const int tid = threadIdx.x, wid = tid >> 6, lane = tid & 63;
  const int wm = wid >> 1, wn = wid & 1;
  const int lane15 = lane & 15, lq = lane >> 4;

  __shared__ __align__(16) char lds[49152];  // A:0  B1:16K  Bg:32K

  const int l8 = lane >> 3, ch = lane & 7;
  long a_byte[4], b_byte[4];
#pragma unroll
  for (int i = 0; i < 4; i++) {
    const int r = wid * 32 + i * 8 + l8;
    const int rr = min(r, rows_valid - 1);
    const int tok = slot_token[kpl * N_TOK + m0 + rr];
    const int chs = ch ^ (r & 7);
    a_byte[i] = ((long)tok * CD + chs * 8) * 2;
    b_byte[i] = ((long)(e * ID + nb + r) * CD + chs * 8) * 2;
  }
  f32x4 acc_h[4][4], acc_g[4][4];
#pragma unroll
  for (int mi = 0; mi < 4; mi++)
#pragma unroll
    for (int ni = 0; ni < 4; ni++) { acc_h[mi][ni] = 0.f; acc_g[mi][ni] = 0.f; }

  for (int kb = 0; kb < CD; kb += BK) {
#pragma unroll
    for (int i = 0; i < 4; i++) {
      __builtin_amdgcn_global_load_lds(
          (const AS1 void*)((const char*)xb + a_byte[i]),
          (AS3 void*)(lds + (wid * 32 + i * 8) * 128), 16, 0, 0);
      a_byte[i] += 128;
    }
#pragma unroll
    for (int i = 0; i < 4; i++) {
      __builtin_amdgcn_global_load_lds(
          (const AS1 void*)((const char*)w1b + b_byte[i]),
          (AS3 void*)(lds + 16384 + (wid * 32 + i * 8) * 128), 16, 0, 0);
      __builtin_amdgcn_global_load_lds(
          (const AS1 void*)((const char*)wgb + b_byte[i]),
          (AS3 void*)(lds + 32768 + (wid * 32 + i * 8) * 128), 16, 0, 0);
      b_byte[i] += 128;
    }
    __syncthreads();
#pragma unroll
    for (int ks = 0; ks < 2; ks++) {
      bf16x8 af[4], bf1[4], bfg[4];
#pragma unroll
      for (int mi = 0; mi < 4; mi++) {
        const int row = wm * 64 + mi * 16 + lane15;
        const int byt = row * 128 + ((ks * 64 + lq * 16) ^ ((row & 7) << 4));
        af[mi] = *(const bf16x8*)(lds + byt);
      }
#pragma unroll
      for (int ni = 0; ni < 4; ni++) {
        const int row = wn * 64 + ni * 16 + lane15;
        const int byt = row * 128 + ((ks * 64 + lq * 16) ^ ((row & 7) << 4));
        bf1[ni] = *(const bf16x8*)(lds + 16384 + byt);
        bfg[ni] = *(const bf16x8*)(lds + 32768 + byt);
      }
#pragma unroll
      for (int mi = 0; mi < 4; mi++)
#pragma unroll
        for (int ni = 0; ni < 4; ni++) {
          acc_h[mi][ni] = __builtin_amdgcn_mfma_f32_16x16x32_bf16(af[mi], bf1[ni], acc_h[mi][ni], 0, 0, 0);
          acc_g[mi][ni] = __builtin_amdgcn_mfma_f32_16x16x32_bf16(af[mi], bfg[ni], acc_g[mi][ni], 0, 0, 0);
        }
    }
    __syncthreads();
  }

  // epilogue: silu(h)*g -> bf16, repack through LDS for coalesced store
  unsigned short* rp = (unsigned short*)lds;
#pragma unroll
  for (int mi = 0; mi < 4; mi++) {
#pragma unroll
    for (int ni = 0; ni < 4; ni++) {
      const int colLoc = wn * 64 + ni * 16 + lane15;
      const float bb1 = b1[e * ID + nb + colLoc];
      const float bbg = bg[e * ID + nb + colLoc];
#pragma unroll
      for (int j = 0; j < 4; j++) {
        const int row = wm * 64 + mi * 16 + lq * 4 + j;
        const float h = acc_h[mi][ni][j] + bb1;
        const float g = acc_g[mi][ni][j] + bbg;
        const float sv = h / (1.f + __expf(-h));
        rp[row * 128 + colLoc] = f2bf(sv * g);
      }
    }
  }
  __syncthreads();
  const long base = ((long)(kpl * N_TOK + m0)) * ID + nb;
#pragma unroll
  for (int it = 0; it < 8; it++) {
    const int chunk = it * 256 + tid;
    const int row = chunk >> 4;
    const int cc = (chunk & 15) * 8;
    if (row < rows_valid)
      *(uint4*)(act + base + (long)row * ID + cc) = *(const uint4*)(rp + row * 128 + cc);
  }
}

// ---------------- phase 2: out (=/+=) w * (act W2 + b2) ----------------
__global__ __launch_bounds__(256, 2) void moe_phase2(
    const unsigned short* __restrict__ act, const unsigned short* __restrict__ w2b,
    const float* __restrict__ b2, const int* __restrict__ slot_token,
    const float* __restrict__ slot_w, float* __restrict__ out,
    const int* __restrict__ meta, const int kpl) {
  const int* counts = meta;
  const int* offs = meta + 16;
  const int* TO = meta + 48 + kpl * 9;
  const int mt = blockIdx.x;
  if (mt >= TO[8]) return;
  int e = 0;
#pragma unroll
  for (int q = 1; q < 8; q++) if (mt >= TO[q]) e = q;
  const int seg_start = offs[kpl * 8 + e];
  const int seg_n = counts[kpl * 8 + e];
  const int m0 = seg_start + (mt - TO[e]) * BM;
  const int rows_valid = min(BM, seg_start + seg_n - m0);
  const int nb = blockIdx.y * BN;
  const int tid = threadIdx.x, wid = tid >> 6, lane = tid & 63;
  const int wm = wid >> 1, wn = wid & 1;
  const int lane15 = lane & 15, lq = lane >> 4;

  __shared__ __align__(16) char lds[32768];  // A:0  B:16K

  const int l8 = lane >> 3, ch = lane & 7;
  long a_byte[4], b_byte[4];
#pragma unroll
  for (int i = 0; i < 4; i++) {
    const int r = wid * 32 + i * 8 + l8;
    const int rr = min(r, rows_valid - 1);
    const int chs = ch ^ (r & 7);
    a_byte[i] = ((long)(kpl * N_TOK + m0 + rr) * ID + chs * 8) * 2;
    b_byte[i] = ((long)(e * CD + nb + r) * ID + chs * 8) * 2;
  }
  f32x4 acc[4][4];
#pragma unroll
  for (int mi = 0; mi < 4; mi++)
#pragma unroll
    for (int ni = 0; ni < 4; ni++) acc[mi][ni] = 0.f;

  for (int kb = 0; kb < ID; kb += BK) {
#pragma unroll
    for (int i = 0; i < 4; i++) {
      __builtin_amdgcn_global_load_lds(
          (const AS1 void*)((const char*)act + a_byte[i]),
          (AS3 void*)(lds + (wid * 32 + i * 8) * 128), 16, 0, 0);
      a_byte[i] += 128;
    }
#pragma unroll
    for (int i = 0; i < 4; i++) {
      __builtin_amdgcn_global_load_lds(
          (const AS1 void*)((const char*)w2b + b_byte[i]),
          (AS3 void*)(lds + 16384 + (wid * 32 + i * 8) * 128), 16, 0, 0);
      b_byte[i] += 128;
    }
    __syncthreads();
#pragma unroll
    for (int ks = 0; ks < 2; ks++) {
      bf16x8 af[4], bf2[4];
#pragma unroll
      for (int mi = 0; mi < 4; mi++) {
        const int row = wm * 64 + mi * 16 + lane15;
        const int byt = row * 128 + ((ks * 64 + lq * 16) ^ ((row & 7) << 4));
        af[mi] = *(const bf16x8*)(lds + byt);
      }
#pragma unroll
      for (int ni = 0; ni < 4; ni++) {
        const int row = wn * 64 + ni * 16 + lane15;
        const int byt = row * 128 + ((ks * 64 + lq * 16) ^ ((row & 7) << 4));
        bf2[ni] = *(const bf16x8*)(lds + 16384 + byt);
      }
#pragma unroll
      for (int mi = 0; mi < 4; mi++)
#pragma unroll
        for (int ni = 0; ni < 4; ni++)
          acc[mi][ni] = __builtin_amdgcn_mfma_f32_16x16x32_bf16(af[mi], bf2[ni], acc[mi][ni], 0, 0, 0);
    }
    __syncthreads();
  }

#pragma unroll
  for (int mi = 0; mi < 4; mi++) {
    int t4[4]; float w4[4]; int rv[4];
#pragma unroll
    for (int j = 0; j < 4; j++) {
      const int r = wm * 64 + mi * 16 + lq * 4 + j;
      rv[j] = (r < rows_valid);
      const int p = kpl * N_TOK + m0 + min(r, rows_valid - 1);
      t4[j] = slot_token[p];
      w4[j] = slot_w[p];
    }
#pragma unroll
    for (int ni = 0; ni < 4; ni++) {
      const int col = nb + wn * 64 + ni * 16 + lane15;
      const float bb = b2[e * CD + col];
#pragma unroll
      for (int j = 0; j < 4; j++) {
        if (rv[j]) {
          const long o = (long)t4[j] * CD + col;
          const float v = (acc[mi][ni][j] + bb) * w4[j];
          if (kpl == 0) out[o] = v;
          else out[o] += v;
        }
      }
    }
  }
}

extern "C" void kernel_launch(void* const* d_in, const int* in_sizes, int n_in,
                              void* d_out, int out_size, void* d_ws, size_t ws_size,
                              hipStream_t stream) {
  const float* x  = (const float*)d_in[0];
  const float* Wr = (const float*)d_in[1];
  const float* br = (const float*)d_in[2];
  const float* W1 = (const float*)d_in[3];
  const float* b1 = (const float*)d_in[4];
  const float* Wg = (const float*)d_in[5];
  const float* bg = (const float*)d_in[6];
  const float* W2 = (const float*)d_in[7];
  const float* b2 = (const float*)d_in[8];
  float* out = (float*)d_out;
  char* ws = (char*)d_ws;

  unsigned short* xb  = (unsigned short*)(ws + XB_OFF);
  unsigned short* w1b = (unsigned short*)(ws + W1B_OFF);
  unsigned short* wgb = (unsigned short*)(ws + WGB_OFF);
  unsigned short* w2b = (unsigned short*)(ws + W2B_OFF);
  unsigned short* act = (unsigned short*)(ws + ACT_OFF);
  int*   slot_token = (int*)(ws + ST_OFF);
  float* slot_w     = (float*)(ws + SW_OFF);
  int*   tok_e      = (int*)(ws + TE_OFF);
  float* tok_w      = (float*)(ws + TW_OFF);
  int*   meta       = (int*)(ws + META_OFF);

  hipMemsetAsync(meta, 0, 512, stream);
  moe_router_cvt<<<N_TOK, 256, 0, stream>>>(x, Wr, br, xb, tok_e, tok_w, meta);
  moe_offsets<<<1, 1, 0, stream>>>(meta);
  moe_scatter<<<N_TOK / 256, 256, 0, stream>>>(tok_e, tok_w, meta, slot_token, slot_w);
  moe_tw<<<dim3(16, 16, 24), 256, 0, stream>>>(W1, Wg, W2, w1b, wgb, w2b);
  moe_phase1<<<dim3(MAXMT, ID / BN, 2), 256, 0, stream>>>(xb, w1b, wgb, b1, bg, act, slot_token, meta);
  moe_phase2<<<dim3(MAXMT, CD / BN), 256, 0, stream>>>(act, w2b, b2, slot_token, slot_w, out, meta, 0);
  moe_phase2<<<dim3(MAXMT, CD / BN), 256, 0, stream>>>(act, w2b, b2, slot_token, slot_w, out, meta, 1);
}

// Round 4
// 273.754 us; speedup vs baseline: 1.8078x; 1.7614x over previous
//
#include <hip/hip_runtime.h>

#define AS1 __attribute__((address_space(1)))
#define AS3 __attribute__((address_space(3)))

typedef __attribute__((ext_vector_type(8))) short bf16x8;
typedef __attribute__((ext_vector_type(4))) float f32x4;

#define N_TOK 8192
#define CD 1024
#define ID 1024
#define BM 128
#define BN 128
#define BK 64
#define MAXMT 72

// ---- workspace layout (bytes) ----
#define XB_OFF   0LL            // x bf16 [N,C]                16MB
#define W1B_OFF  16777216LL     // W1^T bf16 [E][I][C]         16MB
#define WGB_OFF  33554432LL     // Wg^T bf16 [E][I][C]         16MB
#define W2B_OFF  50331648LL     // W2^T bf16 [E][C][I]         16MB
#define ACT_OFF  67108864LL     // act bf16 [2N][I]            32MB
#define ST_OFF   100663296LL    // slot_token int [2N]
#define SW_OFF   100728832LL    // slot_w float [2N]
#define TE_OFF   100794368LL    // tok_e int [N*2]
#define TW_OFF   100859904LL    // tok_w float [N*2]
#define META_OFF 100925440LL    // counts[16] offs[16] (unused 16) TO[2][9]

static __device__ __forceinline__ unsigned short f2bf(float f) {
  union { float f; unsigned u; } v; v.f = f;
  unsigned r = v.u + 0x7fffu + ((v.u >> 16) & 1u);
  return (unsigned short)(r >> 16);
}

// ---------------- fused router + x fp32->bf16 (NO atomics) ----------------
// Round-3 lesson: 16384 same-line global atomicAdds serialize at ~28 cyc each
// = 193us. Router now only writes tok_e/tok_w; counting moved to moe_sort.
__global__ __launch_bounds__(256) void moe_router_cvt(
    const float* __restrict__ x, const float* __restrict__ Wr,
    const float* __restrict__ br, unsigned short* __restrict__ xb,
    int* __restrict__ tok_e, float* __restrict__ tok_w) {
  const int t = blockIdx.x;
  const int tid = threadIdx.x;
  __shared__ float wr_s[256 * 33];   // Wr, rows of 32 floats padded to 33
  __shared__ float red[8 * 256];     // per-thread partials, [e][tid]
  __shared__ float lg_s[8];

  // ---- stage Wr coalesced: 8 x float4 global, 32 scalar LDS writes ----
#pragma unroll
  for (int k = 0; k < 8; k++) {
    const float4 w = *(const float4*)(Wr + (long)(k * 256 + tid) * 4);
    const int row = k * 32 + (tid >> 3);
    const int col = (tid * 4) & 31;
    float* d = wr_s + row * 33 + col;
    d[0] = w.x; d[1] = w.y; d[2] = w.z; d[3] = w.w;
  }

  // ---- x load + bf16 convert/store (coalesced float4 / uint2) ----
  const int c0 = tid * 4;
  const long xoff = (long)t * CD + c0;
  const float4 xv = *(const float4*)(x + xoff);
  uint2 ob;
  ob.x = (unsigned)f2bf(xv.x) | ((unsigned)f2bf(xv.y) << 16);
  ob.y = (unsigned)f2bf(xv.z) | ((unsigned)f2bf(xv.w) << 16);
  *(uint2*)(xb + xoff) = ob;

  __syncthreads();

  // ---- partial logits: thread's 4 channels x 8 experts, Wr from LDS ----
  const float xj[4] = {xv.x, xv.y, xv.z, xv.w};
  float acc[8];
#pragma unroll
  for (int e = 0; e < 8; e++) acc[e] = 0.f;
  const float* wrow = wr_s + tid * 33;
#pragma unroll
  for (int j = 0; j < 4; j++)
#pragma unroll
    for (int e = 0; e < 8; e++)
      acc[e] += xj[j] * wrow[j * 8 + e];

  // ---- block reduce: LDS transpose + 32-lane shfl tree ----
#pragma unroll
  for (int e = 0; e < 8; e++) red[e * 256 + tid] = acc[e];
  __syncthreads();
  {
    const int e = tid >> 5, l = tid & 31;
    float s = 0.f;
#pragma unroll
    for (int k = 0; k < 8; k++) s += red[e * 256 + l + k * 32];
#pragma unroll
    for (int off = 16; off; off >>= 1) s += __shfl_xor(s, off);
    if (l == 0) lg_s[e] = s;
  }
  __syncthreads();

  if (tid == 0) {
    float lg[8];
#pragma unroll
    for (int e = 0; e < 8; e++) lg[e] = lg_s[e] + br[e];
    int i1 = 0; float m1v = lg[0];
#pragma unroll
    for (int e = 1; e < 8; e++) if (lg[e] > m1v) { m1v = lg[e]; i1 = e; }
    int i2 = -1; float m2v = -1e30f;
#pragma unroll
    for (int e = 0; e < 8; e++) if (e != i1 && lg[e] > m2v) { m2v = lg[e]; i2 = e; }
    float s = 0.f;
#pragma unroll
    for (int e = 0; e < 8; e++) s += __expf(lg[e] - m1v);
    const float w1v = 1.f / s;
    const float w2v = __expf(m2v - m1v) / s;
    tok_e[2 * t] = i1; tok_e[2 * t + 1] = i2;
    tok_w[2 * t] = w1v; tok_w[2 * t + 1] = w2v;
  }
}

// ---------------- sort: counts + offsets + stable scatter, ZERO atomics ----
// One block, 256 threads, each owns 32 consecutive tokens. Histogram in LDS
// (cnt[idx][tid]: addr stride 256 dwords == 0 mod 32 banks -> conflict-free),
// cross-thread exclusive scan via 4 waves x shfl, deterministic token-order
// slot assignment. Replaces moe_offsets + moe_scatter (each was ~190us of
// same-line atomic serialization).
__global__ __launch_bounds__(256) void moe_sort(
    const int* __restrict__ tok_e, const float* __restrict__ tok_w,
    int* __restrict__ meta, int* __restrict__ slot_token,
    float* __restrict__ slot_w) {
  const int tid = threadIdx.x;
  __shared__ int cnt[16 * 256];    // per-thread histogram, then running ctr
  __shared__ int base[16 * 256];   // exclusive prefix per (idx, thread)
  __shared__ int offs_s[16];

#pragma unroll
  for (int c = 0; c < 16; c++) cnt[c * 256 + tid] = 0;
  __syncthreads();

  const int t0 = tid * 32;
#pragma unroll 4
  for (int i = 0; i < 32; i++) {
    const int t = t0 + i;
    const int e0 = tok_e[2 * t];
    const int e1 = tok_e[2 * t + 1];
    cnt[e0 * 256 + tid]++;
    cnt[(8 + e1) * 256 + tid]++;
  }
  __syncthreads();

  // exclusive scan of cnt[c][0..255] -> base[c][.], totals -> meta[c]
  {
    const int w = tid >> 6, lane = tid & 63;
#pragma unroll
    for (int q = 0; q < 4; q++) {
      const int c = w * 4 + q;
      int carry = 0;
#pragma unroll
      for (int ch = 0; ch < 4; ch++) {
        const int v = cnt[c * 256 + ch * 64 + lane];
        int incl = v;
#pragma unroll
        for (int off = 1; off < 64; off <<= 1) {
          const int u = __shfl_up(incl, off);
          if (lane >= off) incl += u;
        }
        base[c * 256 + ch * 64 + lane] = incl - v + carry;
        carry += __shfl(incl, 63);
      }
      if (lane == 0) meta[c] = carry;   // counts
    }
  }
  __syncthreads();

  if (tid == 0) {
    int* counts = meta; int* offs = meta + 16; int* TO = meta + 48;
    for (int k = 0; k < 2; k++) {
      int o = 0, tl = 0;
      TO[k * 9] = 0;
      for (int e = 0; e < 8; e++) {
        offs[k * 8 + e] = o;
        offs_s[k * 8 + e] = o;
        o += counts[k * 8 + e];
        tl += (counts[k * 8 + e] + BM - 1) / BM;
        TO[k * 9 + e + 1] = tl;
      }
    }
  }
  // re-zero cnt as running counters for the assignment pass
  __syncthreads();
#pragma unroll
  for (int c = 0; c < 16; c++) cnt[c * 256 + tid] = 0;
  __syncthreads();

#pragma unroll 4
  for (int i = 0; i < 32; i++) {
    const int t = t0 + i;
#pragma unroll
    for (int k = 0; k < 2; k++) {
      const int e = tok_e[2 * t + k];
      const int idx = k * 8 + e;
      const int r = cnt[idx * 256 + tid]++;
      const int slot = offs_s[idx] + base[idx * 256 + tid] + r;
      slot_token[k * N_TOK + slot] = t;
      slot_w[k * N_TOK + slot] = tok_w[2 * t + k];
    }
  }
}

// ---------------- weight transpose + fp32->bf16 (24 x 1024x1024) ----------------
__global__ __launch_bounds__(256) void moe_tw(const float* __restrict__ W1,
                                              const float* __restrict__ Wg,
                                              const float* __restrict__ W2,
                                              unsigned short* __restrict__ w1b,
                                              unsigned short* __restrict__ wgb,
                                              unsigned short* __restrict__ w2b) {
  const int z = blockIdx.z;
  const float* src; unsigned short* dst;
  if (z < 8)       { src = W1 + (long)z * 1048576;        dst = w1b + (long)z * 1048576; }
  else if (z < 16) { src = Wg + (long)(z - 8) * 1048576;  dst = wgb + (long)(z - 8) * 1048576; }
  else             { src = W2 + (long)(z - 16) * 1048576; dst = w2b + (long)(z - 16) * 1048576; }
  __shared__ float tbuf[64][65];
  const int tx = threadIdx.x & 63, ty = threadIdx.x >> 6;
  const int r0 = blockIdx.y * 64, c0 = blockIdx.x * 64;
#pragma unroll
  for (int j = 0; j < 64; j += 4)
    tbuf[ty + j][tx] = src[(long)(r0 + ty + j) * 1024 + c0 + tx];
  __syncthreads();
#pragma unroll
  for (int j = 0; j < 64; j += 4)
    dst[(long)(c0 + ty + j) * 1024 + r0 + tx] = f2bf(tbuf[tx][ty + j]);
}

// ---------------- phase 1: act = silu(x W1 + b1) * (x Wg + bg) ----------------
__global__ __launch_bounds__(256, 2) void moe_phase1(
    const unsigned short* __restrict__ xb, const unsigned short* __restrict__ w1b,
    const unsigned short* __restrict__ wgb, const float* __restrict__ b1,
    const float* __restrict__ bg, unsigned short* __restrict__ act,
    const int* __restrict__ slot_token, const int* __restrict__ meta) {
  const int kpl = blockIdx.z;
  const int* counts = meta;
  const int* offs = meta + 16;
  const int* TO = meta + 48 + kpl * 9;
  const int mt = blockIdx.x;
  if (mt >= TO[8]) return;
  int e = 0;
#pragma unroll
  for (int q = 1; q < 8; q++) if (mt >= TO[q]) e = q;
  const int seg_start = offs[kpl * 8 + e];
  const int seg_n = counts[kpl * 8 + e];
  const int m0 = seg_start + (mt - TO[e]) * BM;
  const int rows_valid = min(BM, seg_start + seg_n - m0);
  const int nb = blockIdx.y * BN;
  const int tid = threadIdx.x, wid = tid >> 6, lane = tid & 63;
  const int wm = wid >> 1, wn = wid & 1;
  const int lane15 = lane & 15, lq = lane >> 4;

  __shared__ __align__(16) char lds[49152];  // A:0  B1:16K  Bg:32K

  const int l8 = lane >> 3, ch = lane & 7;
  long a_byte[4], b_byte[4];
#pragma unroll
  for (int i = 0; i < 4; i++) {
    const int r = wid * 32 + i * 8 + l8;
    const int rr = min(r, rows_valid - 1);
    const int tok = slot_token[kpl * N_TOK + m0 + rr];
    const int chs = ch ^ (r & 7);
    a_byte[i] = ((long)tok * CD + chs * 8) * 2;
    b_byte[i] = ((long)(e * ID + nb + r) * CD + chs * 8) * 2;
  }
  f32x4 acc_h[4][4], acc_g[4][4];
#pragma unroll
  for (int mi = 0; mi < 4; mi++)
#pragma unroll
    for (int ni = 0; ni < 4; ni++) { acc_h[mi][ni] = 0.f; acc_g[mi][ni] = 0.f; }

  for (int kb = 0; kb < CD; kb += BK) {
#pragma unroll
    for (int i = 0; i < 4; i++) {
      __builtin_amdgcn_global_load_lds(
          (const AS1 void*)((const char*)xb + a_byte[i]),
          (AS3 void*)(lds + (wid * 32 + i * 8) * 128), 16, 0, 0);
      a_byte[i] += 128;
    }
#pragma unroll
    for (int i = 0; i < 4; i++) {
      __builtin_amdgcn_global_load_lds(
          (const AS1 void*)((const char*)w1b + b_byte[i]),
          (AS3 void*)(lds + 16384 + (wid * 32 + i * 8) * 128), 16, 0, 0);
      __builtin_amdgcn_global_load_lds(
          (const AS1 void*)((const char*)wgb + b_byte[i]),
          (AS3 void*)(lds + 32768 + (wid * 32 + i * 8) * 128), 16, 0, 0);
      b_byte[i] += 128;
    }
    __syncthreads();
#pragma unroll
    for (int ks = 0; ks < 2; ks++) {
      bf16x8 af[4], bf1[4], bfg[4];
#pragma unroll
      for (int mi = 0; mi < 4; mi++) {
        const int row = wm * 64 + mi * 16 + lane15;
        const int byt = row * 128 + ((ks * 64 + lq * 16) ^ ((row & 7) << 4));
        af[mi] = *(const bf16x8*)(lds + byt);
      }
#pragma unroll
      for (int ni = 0; ni < 4; ni++) {
        const int row = wn * 64 + ni * 16 + lane15;
        const int byt = row * 128 + ((ks * 64 + lq * 16) ^ ((row & 7) << 4));
        bf1[ni] = *(const bf16x8*)(lds + 16384 + byt);
        bfg[ni] = *(const bf16x8*)(lds + 32768 + byt);
      }
#pragma unroll
      for (int mi = 0; mi < 4; mi++)
#pragma unroll
        for (int ni = 0; ni < 4; ni++) {
          acc_h[mi][ni] = __builtin_amdgcn_mfma_f32_16x16x32_bf16(af[mi], bf1[ni], acc_h[mi][ni], 0, 0, 0);
          acc_g[mi][ni] = __builtin_amdgcn_mfma_f32_16x16x32_bf16(af[mi], bfg[ni], acc_g[mi][ni], 0, 0, 0);
        }
    }
    __syncthreads();
  }

  // epilogue: silu(h)*g -> bf16, repack through LDS for coalesced store
  unsigned short* rp = (unsigned short*)lds;
#pragma unroll
  for (int mi = 0; mi < 4; mi++) {
#pragma unroll
    for (int ni = 0; ni < 4; ni++) {
      const int colLoc = wn * 64 + ni * 16 + lane15;
      const float bb1 = b1[e * ID + nb + colLoc];
      const float bbg = bg[e * ID + nb + colLoc];
#pragma unroll
      for (int j = 0; j < 4; j++) {
        const int row = wm * 64 + mi * 16 + lq * 4 + j;
        const float h = acc_h[mi][ni][j] + bb1;
        const float g = acc_g[mi][ni][j] + bbg;
        const float sv = h / (1.f + __expf(-h));
        rp[row * 128 + colLoc] = f2bf(sv * g);
      }
    }
  }
  __syncthreads();
  const long base = ((long)(kpl * N_TOK + m0)) * ID + nb;
#pragma unroll
  for (int it = 0; it < 8; it++) {
    const int chunk = it * 256 + tid;
    const int row = chunk >> 4;
    const int cc = (chunk & 15) * 8;
    if (row < rows_valid)
      *(uint4*)(act + base + (long)row * ID + cc) = *(const uint4*)(rp + row * 128 + cc);
  }
}

// ---------------- phase 2: out (=/+=) w * (act W2 + b2) ----------------
__global__ __launch_bounds__(256, 2) void moe_phase2(
    const unsigned short* __restrict__ act, const unsigned short* __restrict__ w2b,
    const float* __restrict__ b2, const int* __restrict__ slot_token,
    const float* __restrict__ slot_w, float* __restrict__ out,
    const int* __restrict__ meta, const int kpl) {
  const int* counts = meta;
  const int* offs = meta + 16;
  const int* TO = meta + 48 + kpl * 9;
  const int mt = blockIdx.x;
  if (mt >= TO[8]) return;
  int e = 0;
#pragma unroll
  for (int q = 1; q < 8; q++) if (mt >= TO[q]) e = q;
  const int seg_start = offs[kpl * 8 + e];
  const int seg_n = counts[kpl * 8 + e];
  const int m0 = seg_start + (mt - TO[e]) * BM;
  const int rows_valid = min(BM, seg_start + seg_n - m0);
  const int nb = blockIdx.y * BN;
  const int tid = threadIdx.x, wid = tid >> 6, lane = tid & 63;
  const int wm = wid >> 1, wn = wid & 1;
  const int lane15 = lane & 15, lq = lane >> 4;

  __shared__ __align__(16) char lds[32768];  // A:0  B:16K

  const int l8 = lane >> 3, ch = lane & 7;
  long a_byte[4], b_byte[4];
#pragma unroll
  for (int i = 0; i < 4; i++) {
    const int r = wid * 32 + i * 8 + l8;
    const int rr = min(r, rows_valid - 1);
    const int chs = ch ^ (r & 7);
    a_byte[i] = ((long)(kpl * N_TOK + m0 + rr) * ID + chs * 8) * 2;
    b_byte[i] = ((long)(e * CD + nb + r) * ID + chs * 8) * 2;
  }
  f32x4 acc[4][4];
#pragma unroll
  for (int mi = 0; mi < 4; mi++)
#pragma unroll
    for (int ni = 0; ni < 4; ni++) acc[mi][ni] = 0.f;

  for (int kb = 0; kb < ID; kb += BK) {
#pragma unroll
    for (int i = 0; i < 4; i++) {
      __builtin_amdgcn_global_load_lds(
          (const AS1 void*)((const char*)act + a_byte[i]),
          (AS3 void*)(lds + (wid * 32 + i * 8) * 128), 16, 0, 0);
      a_byte[i] += 128;
    }
#pragma unroll
    for (int i = 0; i < 4; i++) {
      __builtin_amdgcn_global_load_lds(
          (const AS1 void*)((const char*)w2b + b_byte[i]),
          (AS3 void*)(lds + 16384 + (wid * 32 + i * 8) * 128), 16, 0, 0);
      b_byte[i] += 128;
    }
    __syncthreads();
#pragma unroll
    for (int ks = 0; ks < 2; ks++) {
      bf16x8 af[4], bf2[4];
#pragma unroll
      for (int mi = 0; mi < 4; mi++) {
        const int row = wm * 64 + mi * 16 + lane15;
        const int byt = row * 128 + ((ks * 64 + lq * 16) ^ ((row & 7) << 4));
        af[mi] = *(const bf16x8*)(lds + byt);
      }
#pragma unroll
      for (int ni = 0; ni < 4; ni++) {
        const int row = wn * 64 + ni * 16 + lane15;
        const int byt = row * 128 + ((ks * 64 + lq * 16) ^ ((row & 7) << 4));
        bf2[ni] = *(const bf16x8*)(lds + 16384 + byt);
      }
#pragma unroll
      for (int mi = 0; mi < 4; mi++)
#pragma unroll
        for (int ni = 0; ni < 4; ni++)
          acc[mi][ni] = __builtin_amdgcn_mfma_f32_16x16x32_bf16(af[mi], bf2[ni], acc[mi][ni], 0, 0, 0);
    }
    __syncthreads();
  }

#pragma unroll
  for (int mi = 0; mi < 4; mi++) {
    int t4[4]; float w4[4]; int rv[4];
#pragma unroll
    for (int j = 0; j < 4; j++) {
      const int r = wm * 64 + mi * 16 + lq * 4 + j;
      rv[j] = (r < rows_valid);
      const int p = kpl * N_TOK + m0 + min(r, rows_valid - 1);
      t4[j] = slot_token[p];
      w4[j] = slot_w[p];
    }
#pragma unroll
    for (int ni = 0; ni < 4; ni++) {
      const int col = nb + wn * 64 + ni * 16 + lane15;
      const float bb = b2[e * CD + col];
#pragma unroll
      for (int j = 0; j < 4; j++) {
        if (rv[j]) {
          const long o = (long)t4[j] * CD + col;
          const float v = (acc[mi][ni][j] + bb) * w4[j];
          if (kpl == 0) out[o] = v;
          else out[o] += v;
        }
      }
    }
  }
}

extern "C" void kernel_launch(void* const* d_in, const int* in_sizes, int n_in,
                              void* d_out, int out_size, void* d_ws, size_t ws_size,
                              hipStream_t stream) {
  const float* x  = (const float*)d_in[0];
  const float* Wr = (const float*)d_in[1];
  const float* br = (const float*)d_in[2];
  const float* W1 = (const float*)d_in[3];
  const float* b1 = (const float*)d_in[4];
  const float* Wg = (const float*)d_in[5];
  const float* bg = (const float*)d_in[6];
  const float* W2 = (const float*)d_in[7];
  const float* b2 = (const float*)d_in[8];
  float* out = (float*)d_out;
  char* ws = (char*)d_ws;

  unsigned short* xb  = (unsigned short*)(ws + XB_OFF);
  unsigned short* w1b = (unsigned short*)(ws + W1B_OFF);
  unsigned short* wgb = (unsigned short*)(ws + WGB_OFF);
  unsigned short* w2b = (unsigned short*)(ws + W2B_OFF);
  unsigned short* act = (unsigned short*)(ws + ACT_OFF);
  int*   slot_token = (int*)(ws + ST_OFF);
  float* slot_w     = (float*)(ws + SW_OFF);
  int*   tok_e      = (int*)(ws + TE_OFF);
  float* tok_w      = (float*)(ws + TW_OFF);
  int*   meta       = (int*)(ws + META_OFF);

  moe_router_cvt<<<N_TOK, 256, 0, stream>>>(x, Wr, br, xb, tok_e, tok_w);
  moe_sort<<<1, 256, 0, stream>>>(tok_e, tok_w, meta, slot_token, slot_w);
  moe_tw<<<dim3(16, 16, 24), 256, 0, stream>>>(W1, Wg, W2, w1b, wgb, w2b);
  moe_phase1<<<dim3(MAXMT, ID / BN, 2), 256, 0, stream>>>(xb, w1b, wgb, b1, bg, act, slot_token, meta);
  moe_phase2<<<dim3(MAXMT, CD / BN), 256, 0, stream>>>(act, w2b, b2, slot_token, slot_w, out, meta, 0);
  moe_phase2<<<dim3(MAXMT, CD / BN), 256, 0, stream>>>(act, w2b, b2, slot_token, slot_w, out, meta, 1);
}